// Round 5
// baseline (1202.759 us; speedup 1.0000x reference)
//
#include <hip/hip_runtime.h>
#include <hip/hip_bf16.h>

// ExpertMLPsV2: T=4096, H=2048, I=4096, E=8, TOPK=2.
// route -> gu GEMM (fp32 weights fused-converted in staging, DMA act, fused silu*up*aff)
// -> dn GEMM (same staging, dense obuf stores) -> combine (out = sum of slots).
// (identical to round-4 submission; that round died to an infra failure pre-run)

constexpr int kT   = 4096;
constexpr int kH   = 2048;
constexpr int kI   = 4096;
constexpr int kE   = 8;
constexpr int kCap = 4096;

typedef __attribute__((ext_vector_type(8))) short bf16x8;
typedef __attribute__((ext_vector_type(4))) float f32x4;

// ---------------- workspace layout ----------------
constexpr size_t HSB_OFF    = 0;                                  // hs bf16: 16 MiB
constexpr size_t HSB_BYTES  = (size_t)kT * kH * 2;
constexpr size_t HBUF_OFF   = HSB_OFF + HSB_BYTES;                // h bf16 (2T+128) x I
constexpr size_t HBUF_BYTES = (size_t)(2 * kT + 128) * kI * 2;
constexpr size_t CNT_OFF    = HBUF_OFF + HBUF_BYTES;
constexpr size_t OFF_OFF    = CNT_OFF + 256;
constexpr size_t LTOK_OFF   = OFF_OFF + 256;
constexpr size_t LW_OFF     = LTOK_OFF + (size_t)kE * kCap * 4;
constexpr size_t POS_OFF    = LW_OFF + (size_t)kE * kCap * 4;     // (e<<12)|slot, 2/token
constexpr size_t OBUF_OFF   = POS_OFF + (size_t)kT * 2 * 4;       // fp32 8192 x kH = 64 MiB
// total ~146 MiB

__device__ __forceinline__ unsigned short f2bf(float x) {   // RNE f32 -> bf16
  unsigned int u = __float_as_uint(x);
  u += 0x7FFFu + ((u >> 16) & 1u);
  return (unsigned short)(u >> 16);
}
__device__ __forceinline__ unsigned pk2(float a, float b) {
  return (unsigned)f2bf(a) | ((unsigned)f2bf(b) << 16);
}

__device__ __forceinline__ float silu_f(float x) { return x / (1.f + __expf(-x)); }

__device__ __forceinline__ void async_copy16(void* lds, const void* g) {
  __builtin_amdgcn_global_load_lds(
      (const __attribute__((address_space(1))) void*)g,
      (__attribute__((address_space(3))) void*)lds, 16, 0, 0);
}

// [128 rows][64 k] bf16 tile, 16B slots XOR'd with row&7 (conflict-free reads)
__device__ __forceinline__ bf16x8 readT64(const unsigned short* s, int row, int kk) {
  return *(const bf16x8*)((const char*)s + row * 128 + ((((kk >> 3) ^ row) & 7) << 4));
}

// Stage one 64k x 128n fp32 weight tile -> swizzled (n,k) bf16 LDS tile.
// Thread layout: kq=(tid&7)*8 (8 k-rows), nq=(tid>>3)*4 (4 n-cols).
// Global: 8x float4, rows 128B-coalesced across lanes. LDS: 4x b128, all 8
// slots covered per 8 lanes -> writes at the b128 data floor (no conflict).
__device__ __forceinline__ void stage_w(const float* __restrict__ src, int ldn,
                                        unsigned short* __restrict__ sW,
                                        int kq, int nq) {
  float4 r[8];
#pragma unroll
  for (int j = 0; j < 8; ++j) r[j] = *(const float4*)(src + (size_t)j * ldn);
  const float* rp = (const float*)r;
#pragma unroll
  for (int i = 0; i < 4; ++i) {
    const int row = nq + i;
    uint4 v;
    v.x = pk2(rp[0 * 4 + i], rp[1 * 4 + i]);
    v.y = pk2(rp[2 * 4 + i], rp[3 * 4 + i]);
    v.z = pk2(rp[4 * 4 + i], rp[5 * 4 + i]);
    v.w = pk2(rp[6 * 4 + i], rp[7 * 4 + i]);
    *(uint4*)((char*)sW + row * 128 + ((((kq >> 3) ^ row) & 7) << 4)) = v;
  }
}

// ---------------- kernel 1: fp32 -> bf16 hidden states ----------------
__global__ void cvt_hs_kernel(const float* __restrict__ in, unsigned short* __restrict__ out) {
  size_t i = ((size_t)blockIdx.x * 256 + threadIdx.x) * 8;
  float4 a = *(const float4*)(in + i);
  float4 b = *(const float4*)(in + i + 4);
  uint4 v;
  v.x = pk2(a.x, a.y);
  v.y = pk2(a.z, a.w);
  v.z = pk2(b.x, b.y);
  v.w = pk2(b.z, b.w);
  *(uint4*)(out + i) = v;
}

// ---------------- kernel 2: routing ----------------
__global__ void route_kernel(const float* __restrict__ aff, const int* __restrict__ idx,
                             int* counts, int* ltok, float* lw, int* pos) {
  int t = blockIdx.x * 256 + threadIdx.x;
  if (t >= kT) return;
  int e0 = idx[t * 2 + 0];
  int e1 = idx[t * 2 + 1];
  float a0 = aff[t * kE + e0];
  float a1 = aff[t * kE + e1];
  if (e0 == e1) {
    float w = a0 / fmaxf(fabsf(a0), 1e-12f);
    int s = atomicAdd(&counts[e0], 1);
    ltok[e0 * kCap + s] = t;
    lw[e0 * kCap + s]   = w;
    pos[t * 2 + 0] = (e0 << 12) | s;
    pos[t * 2 + 1] = -1;
  } else {
    float d = fmaxf(fabsf(a0) + fabsf(a1), 1e-12f);
    int s0 = atomicAdd(&counts[e0], 1);
    ltok[e0 * kCap + s0] = t;
    lw[e0 * kCap + s0]   = a0 / d;
    int s1 = atomicAdd(&counts[e1], 1);
    ltok[e1 * kCap + s1] = t;
    lw[e1 * kCap + s1]   = a1 / d;
    pos[t * 2 + 0] = (e0 << 12) | s0;
    pos[t * 2 + 1] = (e1 << 12) | s1;
  }
}

__global__ void prefix_kernel(const int* __restrict__ counts, int* offs) {
  if (threadIdx.x == 0 && blockIdx.x == 0) {
    int acc = 0;
    for (int e = 0; e < kE; ++e) { offs[e] = acc; acc += counts[e]; }
  }
}

// ---------------- kernel 3: gate/up GEMM, BK=64, fused weight convert ----------
// grid (I/128, kCap/128, E), 256 threads.
__global__ __launch_bounds__(256, 2)
void gemm_gu_kernel(const unsigned short* __restrict__ hsb,
                    const float* __restrict__ wg,     // (E, H, I) fp32
                    const float* __restrict__ wu,
                    const int* __restrict__ counts, const int* __restrict__ offs,
                    const int* __restrict__ ltok, const float* __restrict__ lw,
                    unsigned short* __restrict__ hbuf) {
  __shared__ __attribute__((aligned(16))) unsigned short sWg[128 * 64];
  __shared__ __attribute__((aligned(16))) unsigned short sWu[128 * 64];
  __shared__ __attribute__((aligned(16))) unsigned short sAct[128 * 64];
  __shared__ float sWt[128];

  const int e   = blockIdx.z;
  const int cnt = counts[e];
  const int m0  = blockIdx.y * 128;
  if (m0 >= cnt) return;
  const int n0   = blockIdx.x * 128;
  const int tid  = threadIdx.x;
  const int lane = tid & 63;
  const int wv   = tid >> 6;
  const int wn   = wv & 1;
  const int wm   = wv >> 1;

  if (tid < 128) {
    int s = m0 + tid;
    sWt[tid] = (s < cnt) ? lw[e * kCap + s] : 0.f;
  }

  // act DMA rows handled by this thread (4 chunks)
  int tokR[4];
#pragma unroll
  for (int it = 0; it < 4; ++it) {
    int s = m0 + (tid >> 3) + it * 32;
    tokR[it] = ltok[e * kCap + (s < cnt ? s : 0)];
  }

  // fused weight staging layout
  const int kq = (tid & 7) * 8;
  const int nq = (tid >> 3) * 4;
  const float* wg_t = wg + (size_t)e * kH * kI + (size_t)kq * kI + n0 + nq;
  const float* wu_t = wu + (size_t)e * kH * kI + (size_t)kq * kI + n0 + nq;

  f32x4 accG[4][4] = {};
  f32x4 accU[4][4] = {};

  for (int kt = 0; kt < kH / 64; ++kt) {
    const int k0 = kt * 64;
    // act: DMA with pre-swizzled source
#pragma unroll
    for (int it = 0; it < 4; ++it) {
      const int c   = it * 256 + tid;
      const int row = it * 32 + (tid >> 3);
      const int kof = k0 + ((((tid & 7) ^ row) & 7) << 3);
      async_copy16((char*)sAct + (size_t)c * 16, hsb + (size_t)tokR[it] * kH + kof);
    }
    // weights: reg-stage fp32, convert, swizzled b128 writes
    stage_w(wg_t + (size_t)k0 * kI, kI, sWg, kq, nq);
    stage_w(wu_t + (size_t)k0 * kI, kI, sWu, kq, nq);
    __syncthreads();
#pragma unroll
    for (int kf = 0; kf < 2; ++kf) {
      const int kk = kf * 32 + (lane >> 4) * 8;
      bf16x8 aG[4], aU[4], bA[4];
#pragma unroll
      for (int i = 0; i < 4; ++i) {
        aG[i] = readT64(sWg, wn * 64 + i * 16 + (lane & 15), kk);
        aU[i] = readT64(sWu, wn * 64 + i * 16 + (lane & 15), kk);
        bA[i] = readT64(sAct, wm * 64 + i * 16 + (lane & 15), kk);
      }
#pragma unroll
      for (int i = 0; i < 4; ++i)
#pragma unroll
        for (int j = 0; j < 4; ++j) {
          accG[i][j] = __builtin_amdgcn_mfma_f32_16x16x32_bf16(aG[i], bA[j], accG[i][j], 0, 0, 0);
          accU[i][j] = __builtin_amdgcn_mfma_f32_16x16x32_bf16(aU[i], bA[j], accU[i][j], 0, 0, 0);
        }
    }
    __syncthreads();
  }

  const int lrow = (lane >> 4) * 4;
  const int lcol = lane & 15;
  const size_t rowbase = (size_t)(offs[e] + m0);
#pragma unroll
  for (int i = 0; i < 4; ++i) {
    const int ncol = n0 + wn * 64 + i * 16 + lrow;
#pragma unroll
    for (int j = 0; j < 4; ++j) {
      const int mloc = wm * 64 + j * 16 + lcol;
      if (m0 + mloc < cnt) {
        const float wgt = sWt[mloc];
        f32x4 g = accG[i][j], u = accU[i][j];
        float h0 = silu_f(g[0]) * u[0] * wgt;
        float h1 = silu_f(g[1]) * u[1] * wgt;
        float h2 = silu_f(g[2]) * u[2] * wgt;
        float h3 = silu_f(g[3]) * u[3] * wgt;
        uint2 v;
        v.x = pk2(h0, h1);
        v.y = pk2(h2, h3);
        *(uint2*)(hbuf + ((rowbase + mloc) * kI + ncol)) = v;
      }
    }
  }
}

// ---------------- kernel 4: down GEMM, BK=64, fused weight convert, dense stores
// grid (H/128, kCap/128, E), 256 threads.
__global__ __launch_bounds__(256, 3)
void gemm_dn_kernel(const unsigned short* __restrict__ hbuf,
                    const float* __restrict__ wd,     // (E, I, H) fp32
                    const int* __restrict__ counts, const int* __restrict__ offs,
                    float* __restrict__ obuf) {
  __shared__ __attribute__((aligned(16))) unsigned short sW[128 * 64];
  __shared__ __attribute__((aligned(16))) unsigned short sAct[128 * 64];

  const int e   = blockIdx.z;
  const int cnt = counts[e];
  const int m0  = blockIdx.y * 128;
  if (m0 >= cnt) return;
  const int n0   = blockIdx.x * 128;
  const int tid  = threadIdx.x;
  const int lane = tid & 63;
  const int wv   = tid >> 6;
  const int wn   = wv & 1;
  const int wm   = wv >> 1;
  const int base_row = offs[e] + m0;

  const unsigned short* act_b = hbuf + (size_t)base_row * kI;
  const int kq = (tid & 7) * 8;
  const int nq = (tid >> 3) * 4;
  const float* wd_t = wd + (size_t)e * kI * kH + (size_t)kq * kH + n0 + nq;

  f32x4 acc[4][4] = {};

  for (int kt = 0; kt < kI / 64; ++kt) {
    const int k0 = kt * 64;
#pragma unroll
    for (int it = 0; it < 4; ++it) {
      const int c   = it * 256 + tid;
      const int row = it * 32 + (tid >> 3);
      const int kof = k0 + ((((tid & 7) ^ row) & 7) << 3);
      async_copy16((char*)sAct + (size_t)c * 16, act_b + (size_t)row * kI + kof);
    }
    stage_w(wd_t + (size_t)k0 * kH, kH, sW, kq, nq);
    __syncthreads();
#pragma unroll
    for (int kf = 0; kf < 2; ++kf) {
      const int kk = kf * 32 + (lane >> 4) * 8;
      bf16x8 aW[4], aA[4];
#pragma unroll
      for (int i = 0; i < 4; ++i) {
        aW[i] = readT64(sW, wn * 64 + i * 16 + (lane & 15), kk);
        aA[i] = readT64(sAct, wm * 64 + i * 16 + (lane & 15), kk);
      }
#pragma unroll
      for (int i = 0; i < 4; ++i)
#pragma unroll
        for (int j = 0; j < 4; ++j)
          acc[i][j] = __builtin_amdgcn_mfma_f32_16x16x32_bf16(aW[i], aA[j], acc[i][j], 0, 0, 0);
    }
    __syncthreads();
  }

  const int lrow = (lane >> 4) * 4;
  const int lcol = lane & 15;
#pragma unroll
  for (int i = 0; i < 4; ++i) {
    const int ncol = n0 + wn * 64 + i * 16 + lrow;
#pragma unroll
    for (int j = 0; j < 4; ++j) {
      const int mloc = wm * 64 + j * 16 + lcol;
      if (m0 + mloc < cnt)
        *(f32x4*)(obuf + (size_t)(base_row + mloc) * kH + ncol) = acc[i][j];
    }
  }
}

// ---------------- kernel 5: combine obuf slots -> out ----------------
__global__ void combine_kernel(const float* __restrict__ obuf,
                               const int* __restrict__ pos,
                               const int* __restrict__ offs,
                               float* __restrict__ out) {
  const int t   = blockIdx.y;
  const int col = blockIdx.x * 1024 + threadIdx.x * 4;
  const int c0  = pos[t * 2 + 0];
  const int c1  = pos[t * 2 + 1];
  const int row0 = offs[c0 >> 12] + (c0 & 4095);
  float4 v = *(const float4*)(obuf + (size_t)row0 * kH + col);
  if (c1 >= 0) {
    const int row1 = offs[c1 >> 12] + (c1 & 4095);
    float4 w = *(const float4*)(obuf + (size_t)row1 * kH + col);
    v.x += w.x; v.y += w.y; v.z += w.z; v.w += w.w;
  }
  *(float4*)(out + (size_t)t * kH + col) = v;
}

// ---------------- launcher ----------------
extern "C" void kernel_launch(void* const* d_in, const int* in_sizes, int n_in,
                              void* d_out, int out_size, void* d_ws, size_t ws_size,
                              hipStream_t stream) {
  const float* hs   = (const float*)d_in[0];
  const float* aff  = (const float*)d_in[1];
  const int*   eidx = (const int*)d_in[2];
  const float* wg   = (const float*)d_in[3];
  const float* wu   = (const float*)d_in[4];
  const float* wd   = (const float*)d_in[5];
  float* out = (float*)d_out;

  char* ws = (char*)d_ws;
  unsigned short* hsb  = (unsigned short*)(ws + HSB_OFF);
  unsigned short* hbuf = (unsigned short*)(ws + HBUF_OFF);
  int*            cnts = (int*)(ws + CNT_OFF);
  int*            offs = (int*)(ws + OFF_OFF);
  int*            ltok = (int*)(ws + LTOK_OFF);
  float*          lwgt = (float*)(ws + LW_OFF);
  int*            pos  = (int*)(ws + POS_OFF);
  float*          obuf = (float*)(ws + OBUF_OFF);

  hipMemsetAsync(cnts, 0, kE * sizeof(int), stream);

  cvt_hs_kernel<<<(kT * kH) / (256 * 8), 256, 0, stream>>>(hs, hsb);
  route_kernel<<<kT / 256, 256, 0, stream>>>(aff, eidx, cnts, ltok, lwgt, pos);
  prefix_kernel<<<1, 64, 0, stream>>>(cnts, offs);

  gemm_gu_kernel<<<dim3(kI / 128, kCap / 128, kE), 256, 0, stream>>>(
      hsb, wg, wu, cnts, offs, ltok, lwgt, hbuf);
  gemm_dn_kernel<<<dim3(kH / 128, kCap / 128, kE), 256, 0, stream>>>(
      hbuf, wd, cnts, offs, obuf);
  combine_kernel<<<dim3(kH / 1024, kT), 256, 0, stream>>>(obuf, pos, offs, out);
}

// Round 6
// 1034.180 us; speedup vs baseline: 1.1630x; 1.1630x over previous
//
#include <hip/hip_runtime.h>
#include <hip/hip_bf16.h>

// ExpertMLPsV2: T=4096, H=2048, I=4096, E=8, TOPK=2.
// cvt/route -> tcvt weights to bf16 (N,K) -> gate GEMM256 -> up GEMM256 (fused
// silu*g*u*aff) -> tcvt wd -> down GEMM256 (fp32 obuf) -> combine.
// GEMM256: 256x256 tile, BK=64, 8 waves, dbuf LDS, single-barrier counted-vmcnt
// pipeline (T3/T4) + setprio (T5). All LDS operands DMA-staged, conflict-free swizzle.

constexpr int kT   = 4096;
constexpr int kH   = 2048;
constexpr int kI   = 4096;
constexpr int kE   = 8;
constexpr int kCap = 4096;
constexpr int kRowsCap = 10240;   // 8192 slots + 8*255 align pad, rounded

typedef __attribute__((ext_vector_type(8))) short bf16x8;
typedef __attribute__((ext_vector_type(4))) float f32x4;

// ---------------- workspace layout (regions reused over time) ----------------
// RA: wgT -> wdT      RB: wuT -> obuf      RC: gbuf
constexpr size_t HSB_OFF  = 0;                                   // hs bf16 16 MiB
constexpr size_t HBUF_OFF = 16777216;                            // h bf16 rowsCap x kI
constexpr size_t RA_OFF   = HBUF_OFF + (size_t)kRowsCap * kI * 2;   // 128 MiB
constexpr size_t RB_OFF   = RA_OFF + (size_t)kE * kH * kI * 2;      // 128 MiB
constexpr size_t RC_OFF   = RB_OFF + (size_t)kE * kH * kI * 2;      // 80 MiB (gbuf)
constexpr size_t CNT_OFF  = RC_OFF + (size_t)kRowsCap * kI * 2;
constexpr size_t OFF_OFF  = CNT_OFF + 256;
constexpr size_t LTOK_OFF = OFF_OFF + 256;
constexpr size_t LW_OFF   = LTOK_OFF + (size_t)kE * kCap * 4;
constexpr size_t POS_OFF  = LW_OFF + (size_t)kE * kCap * 4;
constexpr size_t WROW_OFF = POS_OFF + (size_t)kT * 2 * 4;
// end ~453.4 MiB

__device__ __forceinline__ unsigned short f2bf(float x) {   // RNE f32->bf16
  unsigned int u = __float_as_uint(x);
  u += 0x7FFFu + ((u >> 16) & 1u);
  return (unsigned short)(u >> 16);
}
__device__ __forceinline__ unsigned pk2(float a, float b) {
  return (unsigned)f2bf(a) | ((unsigned)f2bf(b) << 16);
}
__device__ __forceinline__ float silu_f(float x) { return x / (1.f + __expf(-x)); }

__device__ __forceinline__ void async_copy16(void* lds, const void* g) {
  __builtin_amdgcn_global_load_lds(
      (const __attribute__((address_space(1))) void*)g,
      (__attribute__((address_space(3))) void*)lds, 16, 0, 0);
}

// [R rows][64 k] bf16 tile, 16B slots XOR'd with row&7 (proven conflict-free)
__device__ __forceinline__ bf16x8 readT64(const unsigned short* s, int row, int kk) {
  return *(const bf16x8*)((const char*)s + row * 128 + ((((kk >> 3) ^ row) & 7) << 4));
}

// ---------------- kernel 1: fp32 -> bf16 hidden states ----------------
__global__ void cvt_hs_kernel(const float* __restrict__ in, unsigned short* __restrict__ out) {
  size_t i = ((size_t)blockIdx.x * 256 + threadIdx.x) * 8;
  float4 a = *(const float4*)(in + i);
  float4 b = *(const float4*)(in + i + 4);
  uint4 v;
  v.x = pk2(a.x, a.y); v.y = pk2(a.z, a.w);
  v.z = pk2(b.x, b.y); v.w = pk2(b.z, b.w);
  *(uint4*)(out + i) = v;
}

// ---------------- kernel 1b: transpose+convert (K,N) f32 -> (N,K) bf16 -------
__global__ __launch_bounds__(256)
void tcvt_kernel(const float* __restrict__ src, unsigned short* __restrict__ dst,
                 int K, int N) {
  __shared__ __attribute__((aligned(16))) unsigned short s[64][72];
  const size_t mat = (size_t)K * N;
  const float* S = src + (size_t)blockIdx.z * mat;
  unsigned short* D = dst + (size_t)blockIdx.z * mat;
  const int k0 = blockIdx.y * 64, n0 = blockIdx.x * 64;
  const int t  = threadIdx.x;
  const int n4 = (t & 15) * 4;
  const int k4 = (t >> 4) * 4;
  const float* p0 = S + (size_t)(k0 + k4) * N + n0 + n4;
  float4 r0 = *(const float4*)(p0);
  float4 r1 = *(const float4*)(p0 + N);
  float4 r2 = *(const float4*)(p0 + 2 * (size_t)N);
  float4 r3 = *(const float4*)(p0 + 3 * (size_t)N);
  uint2 v;
  v.x = pk2(r0.x, r1.x); v.y = pk2(r2.x, r3.x); *(uint2*)(&s[n4 + 0][k4]) = v;
  v.x = pk2(r0.y, r1.y); v.y = pk2(r2.y, r3.y); *(uint2*)(&s[n4 + 1][k4]) = v;
  v.x = pk2(r0.z, r1.z); v.y = pk2(r2.z, r3.z); *(uint2*)(&s[n4 + 2][k4]) = v;
  v.x = pk2(r0.w, r1.w); v.y = pk2(r2.w, r3.w); *(uint2*)(&s[n4 + 3][k4]) = v;
  __syncthreads();
  const int nn = t >> 3;
  const int kc = (t & 7) * 8;
#pragma unroll
  for (int i = 0; i < 2; ++i) {
    const int n = nn + i * 32;
    uint4 u = *(const uint4*)(&s[n][kc]);
    *(uint4*)(D + (size_t)(n0 + n) * K + k0 + kc) = u;
  }
}

// ---------------- kernel 2: routing ----------------
__global__ void route_kernel(const float* __restrict__ aff, const int* __restrict__ idx,
                             int* counts, int* ltok, float* lw, int* pos) {
  int t = blockIdx.x * 256 + threadIdx.x;
  if (t >= kT) return;
  int e0 = idx[t * 2 + 0];
  int e1 = idx[t * 2 + 1];
  float a0 = aff[t * kE + e0];
  float a1 = aff[t * kE + e1];
  if (e0 == e1) {
    float w = a0 / fmaxf(fabsf(a0), 1e-12f);
    int s = atomicAdd(&counts[e0], 1);
    ltok[e0 * kCap + s] = t;
    lw[e0 * kCap + s]   = w;
    pos[t * 2 + 0] = (e0 << 12) | s;
    pos[t * 2 + 1] = -1;
  } else {
    float d = fmaxf(fabsf(a0) + fabsf(a1), 1e-12f);
    int s0 = atomicAdd(&counts[e0], 1);
    ltok[e0 * kCap + s0] = t;
    lw[e0 * kCap + s0]   = a0 / d;
    int s1 = atomicAdd(&counts[e1], 1);
    ltok[e1 * kCap + s1] = t;
    lw[e1 * kCap + s1]   = a1 / d;
    pos[t * 2 + 0] = (e0 << 12) | s0;
    pos[t * 2 + 1] = (e1 << 12) | s1;
  }
}

// 256-aligned prefix offsets
__global__ void prefix_kernel(const int* __restrict__ counts, int* offs) {
  if (threadIdx.x == 0 && blockIdx.x == 0) {
    int acc = 0;
    for (int e = 0; e < kE; ++e) { offs[e] = acc; acc += (counts[e] + 255) & ~255; }
  }
}

// per-slot-row affinity weight (0 for align-pad rows)
__global__ void wrow_kernel(const int* __restrict__ counts, const int* __restrict__ offs,
                            const float* __restrict__ lw, float* __restrict__ wrow) {
  int idx = blockIdx.x * 256 + threadIdx.x;     // e*4096 + s
  int e = idx >> 12, s = idx & 4095;
  int cnt = counts[e];
  int al  = (cnt + 255) & ~255;
  if (s < al) wrow[offs[e] + s] = (s < cnt) ? lw[e * kCap + s] : 0.f;
}

// ---------------- GEMM256: 256x256 tile, BK=64, counted-vmcnt pipeline -------
// EPI 0: store bf16 (gate->gbuf). EPI 1: fuse silu(g)*u*wrow -> bf16 hbuf.
// EPI 2: store f32 (down->obuf). GATHER: A rows via token list.
template<int EPI, int KDIM, int NDIM, bool GATHER>
__global__ __launch_bounds__(512, 2)
void gemm256_kernel(const unsigned short* __restrict__ Abase,
                    const unsigned short* __restrict__ Wmat,   // (E, NDIM, KDIM) bf16
                    unsigned short* __restrict__ outBf,
                    float* __restrict__ outF,
                    const unsigned short* __restrict__ gIn,
                    const float* __restrict__ wrow,
                    const int* __restrict__ counts, const int* __restrict__ offs,
                    const int* __restrict__ ltok) {
  constexpr int TILE = 256 * 64;
  __shared__ __attribute__((aligned(16))) unsigned short sA[2 * TILE];
  __shared__ __attribute__((aligned(16))) unsigned short sW[2 * TILE];

  const int e   = blockIdx.z;
  const int cnt = counts[e];
  const int m0  = blockIdx.y * 256;
  if (m0 >= cnt) return;
  const int n0   = blockIdx.x * 256;
  const int tid  = threadIdx.x;
  const int lane = tid & 63;
  const int wv   = tid >> 6;   // 8 waves: 2(M) x 4(N)
  const int wm   = wv >> 2;
  const int wn   = wv & 3;
  const int baseRow = offs[e] + m0;

  // staging geometry: 2048 16B chunks per operand tile, 4 per thread
  const int srow = tid >> 3;                               // row within 64-group
  const int kof  = (((tid & 7) ^ srow) & 7) << 3;          // pre-swizzled k (bf16)
  const unsigned short* W_e = Wmat + (size_t)e * KDIM * NDIM;
  const unsigned short* aSrc[4];
  const unsigned short* wSrc[4];
#pragma unroll
  for (int it = 0; it < 4; ++it) {
    const int r = it * 64 + srow;
    int arow;
    if (GATHER) {
      int s = m0 + r; s = s < cnt ? s : cnt - 1;
      arow = ltok[e * kCap + s];
    } else {
      arow = baseRow + r;
    }
    aSrc[it] = Abase + (size_t)arow * KDIM + kof;
    wSrc[it] = W_e + (size_t)(n0 + r) * KDIM + kof;
  }

#define STAGE_T(bsel, kk0)                                                     \
  {                                                                            \
    _Pragma("unroll")                                                          \
    for (int it = 0; it < 4; ++it) {                                           \
      const int c = it * 512 + tid;                                            \
      async_copy16((char*)(sA + (bsel) * TILE) + (size_t)c * 16, aSrc[it] + (kk0)); \
      async_copy16((char*)(sW + (bsel) * TILE) + (size_t)c * 16, wSrc[it] + (kk0)); \
    }                                                                          \
  }

  f32x4 acc[8][4] = {};
  STAGE_T(0, 0);

  constexpr int NK = KDIM / 64;
  for (int kt = 0; kt < NK; ++kt) {
    const int cur = kt & 1;
    __builtin_amdgcn_s_barrier();
    if (kt + 1 < NK) {
      STAGE_T(cur ^ 1, (kt + 1) * 64);
      asm volatile("s_waitcnt vmcnt(8)" ::: "memory");   // wait only tile-kt's loads
    } else {
      asm volatile("s_waitcnt vmcnt(0)" ::: "memory");
    }
    const unsigned short* bW = sW + cur * TILE;
    const unsigned short* bA = sA + cur * TILE;
#pragma unroll
    for (int kf = 0; kf < 2; ++kf) {
      const int kk = kf * 32 + (lane >> 4) * 8;
      bf16x8 fW[4], fA[8];
#pragma unroll
      for (int i = 0; i < 4; ++i) fW[i] = readT64(bW, wn * 64 + i * 16 + (lane & 15), kk);
#pragma unroll
      for (int j = 0; j < 8; ++j) fA[j] = readT64(bA, wm * 128 + j * 16 + (lane & 15), kk);
      __builtin_amdgcn_s_setprio(1);
#pragma unroll
      for (int j = 0; j < 8; ++j)
#pragma unroll
        for (int i = 0; i < 4; ++i)
          acc[j][i] = __builtin_amdgcn_mfma_f32_16x16x32_bf16(fW[i], fA[j], acc[j][i], 0, 0, 0);
      __builtin_amdgcn_s_setprio(0);
    }
  }
#undef STAGE_T

  // epilogue: lane holds 4 consecutive n at one m per fragment
  const int lr = (lane >> 4) * 4;
  const int lc = lane & 15;
#pragma unroll
  for (int j = 0; j < 8; ++j) {
    const int grow = baseRow + wm * 128 + j * 16 + lc;
    float wf = 0.f;
    if (EPI == 1) wf = wrow[grow];
#pragma unroll
    for (int i = 0; i < 4; ++i) {
      const int n = n0 + wn * 64 + i * 16 + lr;
      if (EPI == 0) {
        uint2 v;
        v.x = pk2(acc[j][i][0], acc[j][i][1]);
        v.y = pk2(acc[j][i][2], acc[j][i][3]);
        *(uint2*)(outBf + (size_t)grow * NDIM + n) = v;
      } else if (EPI == 1) {
        uint2 gv = *(const uint2*)(gIn + (size_t)grow * NDIM + n);
        float g0 = __uint_as_float(gv.x << 16);
        float g1 = __uint_as_float(gv.x & 0xffff0000u);
        float g2 = __uint_as_float(gv.y << 16);
        float g3 = __uint_as_float(gv.y & 0xffff0000u);
        float h0 = silu_f(g0) * acc[j][i][0] * wf;
        float h1 = silu_f(g1) * acc[j][i][1] * wf;
        float h2 = silu_f(g2) * acc[j][i][2] * wf;
        float h3 = silu_f(g3) * acc[j][i][3] * wf;
        uint2 v;
        v.x = pk2(h0, h1);
        v.y = pk2(h2, h3);
        *(uint2*)(outBf + (size_t)grow * NDIM + n) = v;
      } else {
        *(f32x4*)(outF + (size_t)grow * NDIM + n) = acc[j][i];
      }
    }
  }
}

// ---------------- combine: out[t] = obuf[slot0] (+ obuf[slot1]) ----------------
__global__ void combine_kernel(const float* __restrict__ obuf,
                               const int* __restrict__ pos,
                               const int* __restrict__ offs,
                               float* __restrict__ out) {
  const int t   = blockIdx.y;
  const int col = blockIdx.x * 1024 + threadIdx.x * 4;
  const int c0  = pos[t * 2 + 0];
  const int c1  = pos[t * 2 + 1];
  const int row0 = offs[c0 >> 12] + (c0 & 4095);
  float4 v = *(const float4*)(obuf + (size_t)row0 * kH + col);
  if (c1 >= 0) {
    const int row1 = offs[c1 >> 12] + (c1 & 4095);
    float4 w = *(const float4*)(obuf + (size_t)row1 * kH + col);
    v.x += w.x; v.y += w.y; v.z += w.z; v.w += w.w;
  }
  *(float4*)(out + (size_t)t * kH + col) = v;
}

// ---------------- launcher ----------------
extern "C" void kernel_launch(void* const* d_in, const int* in_sizes, int n_in,
                              void* d_out, int out_size, void* d_ws, size_t ws_size,
                              hipStream_t stream) {
  const float* hs   = (const float*)d_in[0];
  const float* aff  = (const float*)d_in[1];
  const int*   eidx = (const int*)d_in[2];
  const float* wg   = (const float*)d_in[3];
  const float* wu   = (const float*)d_in[4];
  const float* wd   = (const float*)d_in[5];
  float* out = (float*)d_out;

  char* ws = (char*)d_ws;
  unsigned short* hsb  = (unsigned short*)(ws + HSB_OFF);
  unsigned short* hbuf = (unsigned short*)(ws + HBUF_OFF);
  unsigned short* wgT  = (unsigned short*)(ws + RA_OFF);   // later: wdT
  unsigned short* wdT  = (unsigned short*)(ws + RA_OFF);
  unsigned short* wuT  = (unsigned short*)(ws + RB_OFF);   // later: obuf
  float*          obuf = (float*)(ws + RB_OFF);
  unsigned short* gbuf = (unsigned short*)(ws + RC_OFF);
  int*            cnts = (int*)(ws + CNT_OFF);
  int*            offs = (int*)(ws + OFF_OFF);
  int*            ltok = (int*)(ws + LTOK_OFF);
  float*          lwgt = (float*)(ws + LW_OFF);
  int*            pos  = (int*)(ws + POS_OFF);
  float*          wrow = (float*)(ws + WROW_OFF);

  hipMemsetAsync(cnts, 0, kE * sizeof(int), stream);

  cvt_hs_kernel<<<(kT * kH) / (256 * 8), 256, 0, stream>>>(hs, hsb);
  route_kernel<<<kT / 256, 256, 0, stream>>>(aff, eidx, cnts, ltok, lwgt, pos);
  prefix_kernel<<<1, 64, 0, stream>>>(cnts, offs);
  wrow_kernel<<<(kE * kCap) / 256, 256, 0, stream>>>(cnts, offs, lwgt, wrow);

  // weights to bf16 (N,K)
  tcvt_kernel<<<dim3(kI / 64, kH / 64, kE), 256, 0, stream>>>(wg, wgT, kH, kI);
  tcvt_kernel<<<dim3(kI / 64, kH / 64, kE), 256, 0, stream>>>(wu, wuT, kH, kI);

  // gate: g = act . wgT -> gbuf (bf16)
  gemm256_kernel<0, kH, kI, true><<<dim3(kI / 256, kCap / 256, kE), 512, 0, stream>>>(
      hsb, wgT, gbuf, nullptr, nullptr, nullptr, cnts, offs, ltok);
  // up: h = silu(g) * (act . wuT) * aff -> hbuf (bf16)
  gemm256_kernel<1, kH, kI, true><<<dim3(kI / 256, kCap / 256, kE), 512, 0, stream>>>(
      hsb, wuT, hbuf, nullptr, gbuf, wrow, cnts, offs, ltok);

  // wd to bf16 (reuses gbuf region's RA... wdT aliases wgT region; gbuf dead now)
  tcvt_kernel<<<dim3(kH / 64, kI / 64, kE), 256, 0, stream>>>(wd, wdT, kI, kH);

  // down: obuf = h . wdT (fp32), dense per-slot rows
  gemm256_kernel<2, kI, kH, false><<<dim3(kH / 256, kCap / 256, kE), 512, 0, stream>>>(
      hbuf, wdT, nullptr, obuf, nullptr, nullptr, cnts, offs, ltok);

  combine_kernel<<<dim3(kH / 1024, kT), 256, 0, stream>>>(obuf, pos, offs, out);
}

// Round 7
// 786.442 us; speedup vs baseline: 1.5294x; 1.3150x over previous
//
#include <hip/hip_runtime.h>
#include <hip/hip_bf16.h>

// ExpertMLPsV2: T=4096, H=2048, I=4096, E=8, TOPK=2.
// cvt/route -> tcvt weights bf16 (N,K) -> fused gate+up GEMM (ring-4 slice
// pipeline, silu*g*u*aff epilogue) -> tcvt wd -> down GEMM (ring-4) -> combine.
// Ring-4: BK-slice=32, 4 LDS slots, stage slice s+3 while computing slice s,
// boundary s_waitcnt vmcnt(8) (tail 4/0) + barrier. Linear LDS (64B rows are
// bank-balanced for b128 frag reads and DMA writes - no swizzle needed).

constexpr int kT   = 4096;
constexpr int kH   = 2048;
constexpr int kI   = 4096;
constexpr int kE   = 8;
constexpr int kCap = 4096;
constexpr int kRowsCap = 10240;

typedef __attribute__((ext_vector_type(8))) short bf16x8;
typedef __attribute__((ext_vector_type(4))) float f32x4;

// ---------------- workspace layout ----------------
constexpr size_t HSB_OFF  = 0;                                      // hs bf16 16 MiB
constexpr size_t HBUF_OFF = 16777216;                               // h bf16 rowsCap x kI (80 MiB)
constexpr size_t RA_OFF   = HBUF_OFF + (size_t)kRowsCap * kI * 2;   // wgT -> wdT (128 MiB)
constexpr size_t RB_OFF   = RA_OFF + (size_t)kE * kH * kI * 2;      // wuT -> obuf (128 MiB)
constexpr size_t CNT_OFF  = RB_OFF + (size_t)kE * kH * kI * 2;
constexpr size_t OFF_OFF  = CNT_OFF + 256;
constexpr size_t LTOK_OFF = OFF_OFF + 256;
constexpr size_t LW_OFF   = LTOK_OFF + (size_t)kE * kCap * 4;
constexpr size_t POS_OFF  = LW_OFF + (size_t)kE * kCap * 4;
constexpr size_t WROW_OFF = POS_OFF + (size_t)kT * 2 * 4;
// end ~373 MiB

__device__ __forceinline__ unsigned short f2bf(float x) {   // RNE f32->bf16
  unsigned int u = __float_as_uint(x);
  u += 0x7FFFu + ((u >> 16) & 1u);
  return (unsigned short)(u >> 16);
}
__device__ __forceinline__ unsigned pk2(float a, float b) {
  return (unsigned)f2bf(a) | ((unsigned)f2bf(b) << 16);
}
__device__ __forceinline__ float silu_f(float x) { return x / (1.f + __expf(-x)); }

__device__ __forceinline__ void async_copy16(void* lds, const void* g) {
  __builtin_amdgcn_global_load_lds(
      (const __attribute__((address_space(1))) void*)g,
      (__attribute__((address_space(3))) void*)lds, 16, 0, 0);
}

#define MFMA_BF16 __builtin_amdgcn_mfma_f32_16x16x32_bf16

// ---------------- kernel 1: fp32 -> bf16 hidden states ----------------
__global__ void cvt_hs_kernel(const float* __restrict__ in, unsigned short* __restrict__ out) {
  size_t i = ((size_t)blockIdx.x * 256 + threadIdx.x) * 8;
  float4 a = *(const float4*)(in + i);
  float4 b = *(const float4*)(in + i + 4);
  uint4 v;
  v.x = pk2(a.x, a.y); v.y = pk2(a.z, a.w);
  v.z = pk2(b.x, b.y); v.w = pk2(b.z, b.w);
  *(uint4*)(out + i) = v;
}

// ---------------- kernel 1b: transpose+convert (K,N) f32 -> (N,K) bf16 -------
__global__ __launch_bounds__(256)
void tcvt_kernel(const float* __restrict__ src, unsigned short* __restrict__ dst,
                 int K, int N) {
  __shared__ __attribute__((aligned(16))) unsigned short s[64][72];
  const size_t mat = (size_t)K * N;
  const float* S = src + (size_t)blockIdx.z * mat;
  unsigned short* D = dst + (size_t)blockIdx.z * mat;
  const int k0 = blockIdx.y * 64, n0 = blockIdx.x * 64;
  const int t  = threadIdx.x;
  const int n4 = (t & 15) * 4;
  const int k4 = (t >> 4) * 4;
  const float* p0 = S + (size_t)(k0 + k4) * N + n0 + n4;
  float4 r0 = *(const float4*)(p0);
  float4 r1 = *(const float4*)(p0 + N);
  float4 r2 = *(const float4*)(p0 + 2 * (size_t)N);
  float4 r3 = *(const float4*)(p0 + 3 * (size_t)N);
  uint2 v;
  v.x = pk2(r0.x, r1.x); v.y = pk2(r2.x, r3.x); *(uint2*)(&s[n4 + 0][k4]) = v;
  v.x = pk2(r0.y, r1.y); v.y = pk2(r2.y, r3.y); *(uint2*)(&s[n4 + 1][k4]) = v;
  v.x = pk2(r0.z, r1.z); v.y = pk2(r2.z, r3.z); *(uint2*)(&s[n4 + 2][k4]) = v;
  v.x = pk2(r0.w, r1.w); v.y = pk2(r2.w, r3.w); *(uint2*)(&s[n4 + 3][k4]) = v;
  __syncthreads();
  const int nn = t >> 3;
  const int kc = (t & 7) * 8;
#pragma unroll
  for (int i = 0; i < 2; ++i) {
    const int n = nn + i * 32;
    uint4 u = *(const uint4*)(&s[n][kc]);
    *(uint4*)(D + (size_t)(n0 + n) * K + k0 + kc) = u;
  }
}

// ---------------- kernel 2: routing ----------------
__global__ void route_kernel(const float* __restrict__ aff, const int* __restrict__ idx,
                             int* counts, int* ltok, float* lw, int* pos) {
  int t = blockIdx.x * 256 + threadIdx.x;
  if (t >= kT) return;
  int e0 = idx[t * 2 + 0];
  int e1 = idx[t * 2 + 1];
  float a0 = aff[t * kE + e0];
  float a1 = aff[t * kE + e1];
  if (e0 == e1) {
    float w = a0 / fmaxf(fabsf(a0), 1e-12f);
    int s = atomicAdd(&counts[e0], 1);
    ltok[e0 * kCap + s] = t;
    lw[e0 * kCap + s]   = w;
    pos[t * 2 + 0] = (e0 << 12) | s;
    pos[t * 2 + 1] = -1;
  } else {
    float d = fmaxf(fabsf(a0) + fabsf(a1), 1e-12f);
    int s0 = atomicAdd(&counts[e0], 1);
    ltok[e0 * kCap + s0] = t;
    lw[e0 * kCap + s0]   = a0 / d;
    int s1 = atomicAdd(&counts[e1], 1);
    ltok[e1 * kCap + s1] = t;
    lw[e1 * kCap + s1]   = a1 / d;
    pos[t * 2 + 0] = (e0 << 12) | s0;
    pos[t * 2 + 1] = (e1 << 12) | s1;
  }
}

// 256-aligned prefix offsets
__global__ void prefix_kernel(const int* __restrict__ counts, int* offs) {
  if (threadIdx.x == 0 && blockIdx.x == 0) {
    int acc = 0;
    for (int e = 0; e < kE; ++e) { offs[e] = acc; acc += (counts[e] + 255) & ~255; }
  }
}

// per-slot-row affinity weight (0 for align-pad rows)
__global__ void wrow_kernel(const int* __restrict__ counts, const int* __restrict__ offs,
                            const float* __restrict__ lw, float* __restrict__ wrow) {
  int idx = blockIdx.x * 256 + threadIdx.x;
  int e = idx >> 12, s = idx & 4095;
  int cnt = counts[e];
  int al  = (cnt + 255) & ~255;
  if (s < al) wrow[offs[e] + s] = (s < cnt) ? lw[e * kCap + s] : 0.f;
}

// ---------------- kernel 3: fused gate+up GEMM, ring-4 slice pipeline --------
// BM=256, BN=128, slice=32K. 8 waves (2m x 4n), per-wave 128m x 32n per matrix.
// LDS slice slot (32 KiB): A [256][32] @0, Wg [128][32] @16384B, Wu @24576B.
// grid (kI/128, kCap/256, E), 512 threads.
__global__ __launch_bounds__(512, 2)
void gemm_gu_kernel(const unsigned short* __restrict__ hsb,
                    const unsigned short* __restrict__ wgT,   // (E, I, H) bf16
                    const unsigned short* __restrict__ wuT,
                    const int* __restrict__ counts, const int* __restrict__ offs,
                    const int* __restrict__ ltok, const float* __restrict__ wrow,
                    unsigned short* __restrict__ hbuf) {
  constexpr int S = kH / 32;   // 64 slices
  __shared__ __attribute__((aligned(16))) unsigned short lds[4 * 16384];

  const int e   = blockIdx.z;
  const int cnt = counts[e];
  const int m0  = blockIdx.y * 256;
  if (m0 >= cnt) return;
  const int n0   = blockIdx.x * 128;
  const int tid  = threadIdx.x;
  const int lane = tid & 63;
  const int wv   = tid >> 6;
  const int wm   = wv >> 2;       // 2 m-halves of 128
  const int wn   = wv & 3;        // 4 n-panels of 32
  const int baseRow = offs[e] + m0;

  // staging sources: A chunks c=tid (rows 0-127) and c=tid+512 (rows 128-255)
  int sl0 = m0 + (tid >> 2);        sl0 = sl0 < cnt ? sl0 : cnt - 1;
  int sl1 = m0 + 128 + (tid >> 2);  sl1 = sl1 < cnt ? sl1 : cnt - 1;
  const unsigned short* aP0 = hsb + (size_t)ltok[e * kCap + sl0] * kH + (tid & 3) * 8;
  const unsigned short* aP1 = hsb + (size_t)ltok[e * kCap + sl1] * kH + (tid & 3) * 8;
  const unsigned short* wgP = wgT + (size_t)e * kI * kH
                                  + (size_t)(n0 + (tid >> 2)) * kH + (tid & 3) * 8;
  const unsigned short* wuP = wuT + (size_t)e * kI * kH
                                  + (size_t)(n0 + (tid >> 2)) * kH + (tid & 3) * 8;
  char* ldsb = (char*)lds;
  const int aO0 = tid * 16;
  const int aO1 = aO0 + 8192;
  const int wO  = tid * 16;

#define GU_STG_A(s) { const int sb_ = ((s) & 3) * 32768; const int ko_ = (s) * 32;  \
    async_copy16(ldsb + sb_ + aO0, aP0 + ko_);                                      \
    async_copy16(ldsb + sb_ + aO1, aP1 + ko_); }
#define GU_STG_W(s) { const int sb_ = ((s) & 3) * 32768; const int ko_ = (s) * 32;  \
    async_copy16(ldsb + sb_ + 16384 + wO, wgP + ko_);                               \
    async_copy16(ldsb + sb_ + 24576 + wO, wuP + ko_); }

  f32x4 accG[8][2] = {};
  f32x4 accU[8][2] = {};
  const int ar = lane & 15;
  const int fo = (lane >> 4) * 16;   // k-slot byte offset

#define GU_SLICE(s, STG, VM)                                                         \
  {                                                                                  \
    const char* sb = ldsb + ((s) & 3) * 32768;                                       \
    bf16x8 fA[4], fWg[2], fWu[2];                                                    \
    _Pragma("unroll") for (int mf = 0; mf < 4; ++mf)                                 \
      fA[mf] = *(const bf16x8*)(sb + (wm * 128 + mf * 16 + ar) * 64 + fo);           \
    _Pragma("unroll") for (int nf = 0; nf < 2; ++nf) {                               \
      fWg[nf] = *(const bf16x8*)(sb + 16384 + (wn * 32 + nf * 16 + ar) * 64 + fo);   \
      fWu[nf] = *(const bf16x8*)(sb + 24576 + (wn * 32 + nf * 16 + ar) * 64 + fo);   \
    }                                                                                \
    if (STG) GU_STG_A((s) + 3);                                                      \
    __builtin_amdgcn_s_barrier();                                                    \
    __builtin_amdgcn_s_setprio(1);                                                   \
    _Pragma("unroll") for (int mf = 0; mf < 4; ++mf)                                 \
      _Pragma("unroll") for (int nf = 0; nf < 2; ++nf) {                             \
        accG[mf][nf] = MFMA_BF16(fWg[nf], fA[mf], accG[mf][nf], 0, 0, 0);            \
        accU[mf][nf] = MFMA_BF16(fWu[nf], fA[mf], accU[mf][nf], 0, 0, 0);            \
      }                                                                              \
    __builtin_amdgcn_s_setprio(0);                                                   \
    _Pragma("unroll") for (int mf = 0; mf < 4; ++mf)                                 \
      fA[mf] = *(const bf16x8*)(sb + (wm * 128 + (mf + 4) * 16 + ar) * 64 + fo);     \
    if (STG) GU_STG_W((s) + 3);                                                      \
    __builtin_amdgcn_s_barrier();                                                    \
    __builtin_amdgcn_s_setprio(1);                                                   \
    _Pragma("unroll") for (int mf = 0; mf < 4; ++mf)                                 \
      _Pragma("unroll") for (int nf = 0; nf < 2; ++nf) {                             \
        accG[mf + 4][nf] = MFMA_BF16(fWg[nf], fA[mf], accG[mf + 4][nf], 0, 0, 0);    \
        accU[mf + 4][nf] = MFMA_BF16(fWu[nf], fA[mf], accU[mf + 4][nf], 0, 0, 0);    \
      }                                                                              \
    __builtin_amdgcn_s_setprio(0);                                                   \
    if ((VM) >= 0) {                                                                 \
      asm volatile("s_waitcnt vmcnt(%0)" :: "i"((VM) < 0 ? 0 : (VM)) : "memory");    \
      __builtin_amdgcn_s_barrier();                                                  \
    }                                                                                \
  }

  // prologue: slices 0,1,2 in flight; wait slice 0
  GU_STG_A(0); GU_STG_W(0);
  GU_STG_A(1); GU_STG_W(1);
  GU_STG_A(2); GU_STG_W(2);
  asm volatile("s_waitcnt vmcnt(8)" ::: "memory");
  __builtin_amdgcn_s_barrier();

  for (int s = 0; s < S - 3; ++s) GU_SLICE(s, true, 8);
  GU_SLICE(S - 3, false, 4);
  GU_SLICE(S - 2, false, 0);
  GU_SLICE(S - 1, false, -1);
#undef GU_SLICE
#undef GU_STG_A
#undef GU_STG_W

  // epilogue: h = silu(g)*u*wrow -> bf16 hbuf
  const int lr4 = (lane >> 4) * 4;
#pragma unroll
  for (int mf = 0; mf < 8; ++mf) {
    const int grow = baseRow + wm * 128 + mf * 16 + ar;
    const float wf = wrow[grow];
#pragma unroll
    for (int nf = 0; nf < 2; ++nf) {
      const int n = n0 + wn * 32 + nf * 16 + lr4;
      f32x4 g = accG[mf][nf], u = accU[mf][nf];
      float h0 = silu_f(g[0]) * u[0] * wf;
      float h1 = silu_f(g[1]) * u[1] * wf;
      float h2 = silu_f(g[2]) * u[2] * wf;
      float h3 = silu_f(g[3]) * u[3] * wf;
      uint2 v;
      v.x = pk2(h0, h1);
      v.y = pk2(h2, h3);
      *(uint2*)(hbuf + ((size_t)grow * kI + n)) = v;
    }
  }
}

// ---------------- kernel 4: down GEMM, ring-4 slice pipeline ----------------
// BM=256, BN=256, slice=32K. 8 waves (2m x 4n), per-wave 128m x 64n.
// LDS slot (32 KiB): A [256][32] @0, W [256][32] @16384B.
// grid (kH/256, kCap/256, E), 512 threads.
__global__ __launch_bounds__(512, 2)
void gemm_dn_kernel(const unsigned short* __restrict__ hbuf,
                    const unsigned short* __restrict__ wdT,   // (E, H, I) bf16
                    const int* __restrict__ counts, const int* __restrict__ offs,
                    float* __restrict__ obuf) {
  constexpr int S = kI / 32;   // 128 slices
  __shared__ __attribute__((aligned(16))) unsigned short lds[4 * 16384];

  const int e   = blockIdx.z;
  const int cnt = counts[e];
  const int m0  = blockIdx.y * 256;
  if (m0 >= cnt) return;
  const int n0   = blockIdx.x * 256;
  const int tid  = threadIdx.x;
  const int lane = tid & 63;
  const int wv   = tid >> 6;
  const int wm   = wv >> 2;
  const int wn   = wv & 3;
  const int baseRow = offs[e] + m0;

  const unsigned short* aP0 = hbuf + (size_t)(baseRow + (tid >> 2)) * kI + (tid & 3) * 8;
  const unsigned short* aP1 = hbuf + (size_t)(baseRow + 128 + (tid >> 2)) * kI + (tid & 3) * 8;
  const unsigned short* wP0 = wdT + (size_t)e * kH * kI
                                  + (size_t)(n0 + (tid >> 2)) * kI + (tid & 3) * 8;
  const unsigned short* wP1 = wdT + (size_t)e * kH * kI
                                  + (size_t)(n0 + 128 + (tid >> 2)) * kI + (tid & 3) * 8;
  char* ldsb = (char*)lds;
  const int cO0 = tid * 16;
  const int cO1 = cO0 + 8192;

#define DN_STG_A(s) { const int sb_ = ((s) & 3) * 32768; const int ko_ = (s) * 32;  \
    async_copy16(ldsb + sb_ + cO0, aP0 + ko_);                                      \
    async_copy16(ldsb + sb_ + cO1, aP1 + ko_); }
#define DN_STG_W(s) { const int sb_ = ((s) & 3) * 32768; const int ko_ = (s) * 32;  \
    async_copy16(ldsb + sb_ + 16384 + cO0, wP0 + ko_);                              \
    async_copy16(ldsb + sb_ + 16384 + cO1, wP1 + ko_); }

  f32x4 acc[8][4] = {};
  const int ar = lane & 15;
  const int fo = (lane >> 4) * 16;

#define DN_SLICE(s, STG, VM)                                                         \
  {                                                                                  \
    const char* sb = ldsb + ((s) & 3) * 32768;                                       \
    bf16x8 fA[4], fW[4];                                                             \
    _Pragma("unroll") for (int mf = 0; mf < 4; ++mf)                                 \
      fA[mf] = *(const bf16x8*)(sb + (wm * 128 + mf * 16 + ar) * 64 + fo);           \
    _Pragma("unroll") for (int nf = 0; nf < 4; ++nf)                                 \
      fW[nf] = *(const bf16x8*)(sb + 16384 + (wn * 64 + nf * 16 + ar) * 64 + fo);    \
    if (STG) DN_STG_A((s) + 3);                                                      \
    __builtin_amdgcn_s_barrier();                                                    \
    __builtin_amdgcn_s_setprio(1);                                                   \
    _Pragma("unroll") for (int mf = 0; mf < 4; ++mf)                                 \
      _Pragma("unroll") for (int nf = 0; nf < 4; ++nf)                               \
        acc[mf][nf] = MFMA_BF16(fW[nf], fA[mf], acc[mf][nf], 0, 0, 0);               \
    __builtin_amdgcn_s_setprio(0);                                                   \
    _Pragma("unroll") for (int mf = 0; mf < 4; ++mf)                                 \
      fA[mf] = *(const bf16x8*)(sb + (wm * 128 + (mf + 4) * 16 + ar) * 64 + fo);     \
    if (STG) DN_STG_W((s) + 3);                                                      \
    __builtin_amdgcn_s_barrier();                                                    \
    __builtin_amdgcn_s_setprio(1);                                                   \
    _Pragma("unroll") for (int mf = 0; mf < 4; ++mf)                                 \
      _Pragma("unroll") for (int nf = 0; nf < 4; ++nf)                               \
        acc[mf + 4][nf] = MFMA_BF16(fW[nf], fA[mf], acc[mf + 4][nf], 0, 0, 0);       \
    __builtin_amdgcn_s_setprio(0);                                                   \
    if ((VM) >= 0) {                                                                 \
      asm volatile("s_waitcnt vmcnt(%0)" :: "i"((VM) < 0 ? 0 : (VM)) : "memory");    \
      __builtin_amdgcn_s_barrier();                                                  \
    }                                                                                \
  }

  DN_STG_A(0); DN_STG_W(0);
  DN_STG_A(1); DN_STG_W(1);
  DN_STG_A(2); DN_STG_W(2);
  asm volatile("s_waitcnt vmcnt(8)" ::: "memory");
  __builtin_amdgcn_s_barrier();

  for (int s = 0; s < S - 3; ++s) DN_SLICE(s, true, 8);
  DN_SLICE(S - 3, false, 4);
  DN_SLICE(S - 2, false, 0);
  DN_SLICE(S - 1, false, -1);
#undef DN_SLICE
#undef DN_STG_A
#undef DN_STG_W

  const int lr4 = (lane >> 4) * 4;
#pragma unroll
  for (int mf = 0; mf < 8; ++mf) {
    const int grow = baseRow + wm * 128 + mf * 16 + ar;
#pragma unroll
    for (int nf = 0; nf < 4; ++nf) {
      const int n = n0 + wn * 64 + nf * 16 + lr4;
      *(f32x4*)(obuf + (size_t)grow * kH + n) = acc[mf][nf];
    }
  }
}

// ---------------- kernel 5: combine obuf slots -> out ----------------
__global__ void combine_kernel(const float* __restrict__ obuf,
                               const int* __restrict__ pos,
                               const int* __restrict__ offs,
                               float* __restrict__ out) {
  const int t   = blockIdx.y;
  const int col = blockIdx.x * 1024 + threadIdx.x * 4;
  const int c0  = pos[t * 2 + 0];
  const int c1  = pos[t * 2 + 1];
  const int row0 = offs[c0 >> 12] + (c0 & 4095);
  float4 v = *(const float4*)(obuf + (size_t)row0 * kH + col);
  if (c1 >= 0) {
    const int row1 = offs[c1 >> 12] + (c1 & 4095);
    float4 w = *(const float4*)(obuf + (size_t)row1 * kH + col);
    v.x += w.x; v.y += w.y; v.z += w.z; v.w += w.w;
  }
  *(float4*)(out + (size_t)t * kH + col) = v;
}

// ---------------- launcher ----------------
extern "C" void kernel_launch(void* const* d_in, const int* in_sizes, int n_in,
                              void* d_out, int out_size, void* d_ws, size_t ws_size,
                              hipStream_t stream) {
  const float* hs   = (const float*)d_in[0];
  const float* aff  = (const float*)d_in[1];
  const int*   eidx = (const int*)d_in[2];
  const float* wg   = (const float*)d_in[3];
  const float* wu   = (const float*)d_in[4];
  const float* wd   = (const float*)d_in[5];
  float* out = (float*)d_out;

  char* ws = (char*)d_ws;
  unsigned short* hsb  = (unsigned short*)(ws + HSB_OFF);
  unsigned short* hbuf = (unsigned short*)(ws + HBUF_OFF);
  unsigned short* wgT  = (unsigned short*)(ws + RA_OFF);   // later: wdT
  unsigned short* wdT  = (unsigned short*)(ws + RA_OFF);
  unsigned short* wuT  = (unsigned short*)(ws + RB_OFF);   // later: obuf
  float*          obuf = (float*)(ws + RB_OFF);
  int*            cnts = (int*)(ws + CNT_OFF);
  int*            offs = (int*)(ws + OFF_OFF);
  int*            ltok = (int*)(ws + LTOK_OFF);
  float*          lwgt = (float*)(ws + LW_OFF);
  int*            pos  = (int*)(ws + POS_OFF);
  float*          wrow = (float*)(ws + WROW_OFF);

  hipMemsetAsync(cnts, 0, kE * sizeof(int), stream);

  cvt_hs_kernel<<<(kT * kH) / (256 * 8), 256, 0, stream>>>(hs, hsb);
  route_kernel<<<kT / 256, 256, 0, stream>>>(aff, eidx, cnts, ltok, lwgt, pos);
  prefix_kernel<<<1, 64, 0, stream>>>(cnts, offs);
  wrow_kernel<<<(kE * kCap) / 256, 256, 0, stream>>>(cnts, offs, lwgt, wrow);

  tcvt_kernel<<<dim3(kI / 64, kH / 64, kE), 256, 0, stream>>>(wg, wgT, kH, kI);
  tcvt_kernel<<<dim3(kI / 64, kH / 64, kE), 256, 0, stream>>>(wu, wuT, kH, kI);

  gemm_gu_kernel<<<dim3(kI / 128, kCap / 256, kE), 512, 0, stream>>>(
      hsb, wgT, wuT, cnts, offs, ltok, wrow, hbuf);

  tcvt_kernel<<<dim3(kH / 64, kI / 64, kE), 256, 0, stream>>>(wd, wdT, kI, kH);

  gemm_dn_kernel<<<dim3(kH / 256, kCap / 256, kE), 512, 0, stream>>>(
      hbuf, wdT, cnts, offs, obuf);

  combine_kernel<<<dim3(kH / 1024, kT), 256, 0, stream>>>(obuf, pos, offs, out);
}

// Round 8
// 761.683 us; speedup vs baseline: 1.5791x; 1.0325x over previous
//
#include <hip/hip_runtime.h>
#include <hip/hip_bf16.h>

// ExpertMLPsV2: T=4096, H=2048, I=4096, E=8, TOPK=2.
// cvt/route -> tcvt weights bf16 (N,K) -> fused gate+up GEMM (ring-4 slice
// pipeline, silu*g*u*aff epilogue) -> tcvt wd -> down GEMM (ring-4) -> combine.
// Ring-4: BK-slice=32, 4 LDS slots, stage slice s+3 while computing slice s,
// boundary s_waitcnt vmcnt(8) (tail 4/0) + barrier.
// LDS: linear dest for DMA; 16B k-slot XOR-swizzled (s^((row>>1)&3)) via
// pre-swizzled global source; read-side XOR folds into per-lane constant fo.
// Bank check: start bank = 16*row + 4*(slot^((row>>1)&3)) mod 32 -> all 32
// banks covered per 8 rows, 2 lanes/bank = free (m136).

constexpr int kT   = 4096;
constexpr int kH   = 2048;
constexpr int kI   = 4096;
constexpr int kE   = 8;
constexpr int kCap = 4096;
constexpr int kRowsCap = 10240;

typedef __attribute__((ext_vector_type(8))) short bf16x8;
typedef __attribute__((ext_vector_type(4))) float f32x4;

// ---------------- workspace layout ----------------
constexpr size_t HSB_OFF  = 0;                                      // hs bf16 16 MiB
constexpr size_t HBUF_OFF = 16777216;                               // h bf16 rowsCap x kI (80 MiB)
constexpr size_t RA_OFF   = HBUF_OFF + (size_t)kRowsCap * kI * 2;   // wgT -> wdT (128 MiB)
constexpr size_t RB_OFF   = RA_OFF + (size_t)kE * kH * kI * 2;      // wuT -> obuf (128 MiB)
constexpr size_t CNT_OFF  = RB_OFF + (size_t)kE * kH * kI * 2;
constexpr size_t OFF_OFF  = CNT_OFF + 256;
constexpr size_t LTOK_OFF = OFF_OFF + 256;
constexpr size_t LW_OFF   = LTOK_OFF + (size_t)kE * kCap * 4;
constexpr size_t POS_OFF  = LW_OFF + (size_t)kE * kCap * 4;
constexpr size_t WROW_OFF = POS_OFF + (size_t)kT * 2 * 4;
// end ~373 MiB

__device__ __forceinline__ unsigned short f2bf(float x) {   // RNE f32->bf16
  unsigned int u = __float_as_uint(x);
  u += 0x7FFFu + ((u >> 16) & 1u);
  return (unsigned short)(u >> 16);
}
__device__ __forceinline__ unsigned pk2(float a, float b) {
  return (unsigned)f2bf(a) | ((unsigned)f2bf(b) << 16);
}
__device__ __forceinline__ float silu_f(float x) { return x / (1.f + __expf(-x)); }

__device__ __forceinline__ void async_copy16(void* lds, const void* g) {
  __builtin_amdgcn_global_load_lds(
      (const __attribute__((address_space(1))) void*)g,
      (__attribute__((address_space(3))) void*)lds, 16, 0, 0);
}

#define MFMA_BF16 __builtin_amdgcn_mfma_f32_16x16x32_bf16

// ---------------- kernel 1: fp32 -> bf16 hidden states ----------------
__global__ void cvt_hs_kernel(const float* __restrict__ in, unsigned short* __restrict__ out) {
  size_t i = ((size_t)blockIdx.x * 256 + threadIdx.x) * 8;
  float4 a = *(const float4*)(in + i);
  float4 b = *(const float4*)(in + i + 4);
  uint4 v;
  v.x = pk2(a.x, a.y); v.y = pk2(a.z, a.w);
  v.z = pk2(b.x, b.y); v.w = pk2(b.z, b.w);
  *(uint4*)(out + i) = v;
}

// ---------------- kernel 1b: transpose+convert (K,N) f32 -> (N,K) bf16 -------
__global__ __launch_bounds__(256)
void tcvt_kernel(const float* __restrict__ src, unsigned short* __restrict__ dst,
                 int K, int N) {
  __shared__ __attribute__((aligned(16))) unsigned short s[64][72];
  const size_t mat = (size_t)K * N;
  const float* S = src + (size_t)blockIdx.z * mat;
  unsigned short* D = dst + (size_t)blockIdx.z * mat;
  const int k0 = blockIdx.y * 64, n0 = blockIdx.x * 64;
  const int t  = threadIdx.x;
  const int n4 = (t & 15) * 4;
  const int k4 = (t >> 4) * 4;
  const float* p0 = S + (size_t)(k0 + k4) * N + n0 + n4;
  float4 r0 = *(const float4*)(p0);
  float4 r1 = *(const float4*)(p0 + N);
  float4 r2 = *(const float4*)(p0 + 2 * (size_t)N);
  float4 r3 = *(const float4*)(p0 + 3 * (size_t)N);
  uint2 v;
  v.x = pk2(r0.x, r1.x); v.y = pk2(r2.x, r3.x); *(uint2*)(&s[n4 + 0][k4]) = v;
  v.x = pk2(r0.y, r1.y); v.y = pk2(r2.y, r3.y); *(uint2*)(&s[n4 + 1][k4]) = v;
  v.x = pk2(r0.z, r1.z); v.y = pk2(r2.z, r3.z); *(uint2*)(&s[n4 + 2][k4]) = v;
  v.x = pk2(r0.w, r1.w); v.y = pk2(r2.w, r3.w); *(uint2*)(&s[n4 + 3][k4]) = v;
  __syncthreads();
  const int nn = t >> 3;
  const int kc = (t & 7) * 8;
#pragma unroll
  for (int i = 0; i < 2; ++i) {
    const int n = nn + i * 32;
    uint4 u = *(const uint4*)(&s[n][kc]);
    *(uint4*)(D + (size_t)(n0 + n) * K + k0 + kc) = u;
  }
}

// ---------------- kernel 2: routing ----------------
__global__ void route_kernel(const float* __restrict__ aff, const int* __restrict__ idx,
                             int* counts, int* ltok, float* lw, int* pos) {
  int t = blockIdx.x * 256 + threadIdx.x;
  if (t >= kT) return;
  int e0 = idx[t * 2 + 0];
  int e1 = idx[t * 2 + 1];
  float a0 = aff[t * kE + e0];
  float a1 = aff[t * kE + e1];
  if (e0 == e1) {
    float w = a0 / fmaxf(fabsf(a0), 1e-12f);
    int s = atomicAdd(&counts[e0], 1);
    ltok[e0 * kCap + s] = t;
    lw[e0 * kCap + s]   = w;
    pos[t * 2 + 0] = (e0 << 12) | s;
    pos[t * 2 + 1] = -1;
  } else {
    float d = fmaxf(fabsf(a0) + fabsf(a1), 1e-12f);
    int s0 = atomicAdd(&counts[e0], 1);
    ltok[e0 * kCap + s0] = t;
    lw[e0 * kCap + s0]   = a0 / d;
    int s1 = atomicAdd(&counts[e1], 1);
    ltok[e1 * kCap + s1] = t;
    lw[e1 * kCap + s1]   = a1 / d;
    pos[t * 2 + 0] = (e0 << 12) | s0;
    pos[t * 2 + 1] = (e1 << 12) | s1;
  }
}

// 256-aligned prefix offsets
__global__ void prefix_kernel(const int* __restrict__ counts, int* offs) {
  if (threadIdx.x == 0 && blockIdx.x == 0) {
    int acc = 0;
    for (int e = 0; e < kE; ++e) { offs[e] = acc; acc += (counts[e] + 255) & ~255; }
  }
}

// per-slot-row affinity weight (0 for align-pad rows)
__global__ void wrow_kernel(const int* __restrict__ counts, const int* __restrict__ offs,
                            const float* __restrict__ lw, float* __restrict__ wrow) {
  int idx = blockIdx.x * 256 + threadIdx.x;
  int e = idx >> 12, s = idx & 4095;
  int cnt = counts[e];
  int al  = (cnt + 255) & ~255;
  if (s < al) wrow[offs[e] + s] = (s < cnt) ? lw[e * kCap + s] : 0.f;
}

// ---------------- kernel 3: fused gate+up GEMM, ring-4 slice pipeline --------
// BM=256, BN=128, slice=32K. 8 waves (2m x 4n), per-wave 128m x 32n per matrix.
// LDS slice slot (32 KiB): A [256][32] @0, Wg [128][32] @16384B, Wu @24576B.
// grid (kI/128, kCap/256, E), 512 threads.
__global__ __launch_bounds__(512, 2)
void gemm_gu_kernel(const unsigned short* __restrict__ hsb,
                    const unsigned short* __restrict__ wgT,   // (E, I, H) bf16
                    const unsigned short* __restrict__ wuT,
                    const int* __restrict__ counts, const int* __restrict__ offs,
                    const int* __restrict__ ltok, const float* __restrict__ wrow,
                    unsigned short* __restrict__ hbuf) {
  constexpr int S = kH / 32;   // 64 slices
  __shared__ __attribute__((aligned(16))) unsigned short lds[4 * 16384];

  const int e   = blockIdx.z;
  const int cnt = counts[e];
  const int m0  = blockIdx.y * 256;
  if (m0 >= cnt) return;
  const int n0   = blockIdx.x * 128;
  const int tid  = threadIdx.x;
  const int lane = tid & 63;
  const int wv   = tid >> 6;
  const int wm   = wv >> 2;       // 2 m-halves of 128
  const int wn   = wv & 3;        // 4 n-panels of 32
  const int baseRow = offs[e] + m0;

  // staging: chunk (row = tid>>2, physical slot = tid&3) holds logical slot
  // (tid&3)^((row>>1)&3) = (tid&3)^((tid>>3)&3)  [involution]
  const int skof = ((tid & 3) ^ ((tid >> 3) & 3)) * 8;   // source k offset (bf16)
  int sl0 = m0 + (tid >> 2);        sl0 = sl0 < cnt ? sl0 : cnt - 1;
  int sl1 = m0 + 128 + (tid >> 2);  sl1 = sl1 < cnt ? sl1 : cnt - 1;
  const unsigned short* aP0 = hsb + (size_t)ltok[e * kCap + sl0] * kH + skof;
  const unsigned short* aP1 = hsb + (size_t)ltok[e * kCap + sl1] * kH + skof;
  const unsigned short* wgP = wgT + (size_t)e * kI * kH
                                  + (size_t)(n0 + (tid >> 2)) * kH + skof;
  const unsigned short* wuP = wuT + (size_t)e * kI * kH
                                  + (size_t)(n0 + (tid >> 2)) * kH + skof;
  char* ldsb = (char*)lds;
  const int aO0 = tid * 16;
  const int aO1 = aO0 + 8192;
  const int wO  = tid * 16;

#define GU_STG_A(s) { const int sb_ = ((s) & 3) * 32768; const int ko_ = (s) * 32;  \
    async_copy16(ldsb + sb_ + aO0, aP0 + ko_);                                      \
    async_copy16(ldsb + sb_ + aO1, aP1 + ko_); }
#define GU_STG_W(s) { const int sb_ = ((s) & 3) * 32768; const int ko_ = (s) * 32;  \
    async_copy16(ldsb + sb_ + 16384 + wO, wgP + ko_);                               \
    async_copy16(ldsb + sb_ + 24576 + wO, wuP + ko_); }

  f32x4 accG[8][2] = {};
  f32x4 accU[8][2] = {};
  const int ar = lane & 15;
  // read-side k-slot with XOR swizzle folded in: rows are base+ar with base
  // multiple of 16, so (row>>1)&3 = (lane>>1)&3 -> per-lane constant.
  const int fo = (((lane >> 4) ^ ((lane >> 1) & 3)) << 4);

#define GU_SLICE(s, STG, VM)                                                         \
  {                                                                                  \
    const char* sb = ldsb + ((s) & 3) * 32768;                                       \
    bf16x8 fA[4], fWg[2], fWu[2];                                                    \
    _Pragma("unroll") for (int mf = 0; mf < 4; ++mf)                                 \
      fA[mf] = *(const bf16x8*)(sb + (wm * 128 + mf * 16 + ar) * 64 + fo);           \
    _Pragma("unroll") for (int nf = 0; nf < 2; ++nf) {                               \
      fWg[nf] = *(const bf16x8*)(sb + 16384 + (wn * 32 + nf * 16 + ar) * 64 + fo);   \
      fWu[nf] = *(const bf16x8*)(sb + 24576 + (wn * 32 + nf * 16 + ar) * 64 + fo);   \
    }                                                                                \
    if (STG) GU_STG_A((s) + 3);                                                      \
    __builtin_amdgcn_s_barrier();                                                    \
    __builtin_amdgcn_s_setprio(1);                                                   \
    _Pragma("unroll") for (int mf = 0; mf < 4; ++mf)                                 \
      _Pragma("unroll") for (int nf = 0; nf < 2; ++nf) {                             \
        accG[mf][nf] = MFMA_BF16(fWg[nf], fA[mf], accG[mf][nf], 0, 0, 0);            \
        accU[mf][nf] = MFMA_BF16(fWu[nf], fA[mf], accU[mf][nf], 0, 0, 0);            \
      }                                                                              \
    __builtin_amdgcn_s_setprio(0);                                                   \
    _Pragma("unroll") for (int mf = 0; mf < 4; ++mf)                                 \
      fA[mf] = *(const bf16x8*)(sb + (wm * 128 + (mf + 4) * 16 + ar) * 64 + fo);     \
    if (STG) GU_STG_W((s) + 3);                                                      \
    __builtin_amdgcn_s_barrier();                                                    \
    __builtin_amdgcn_s_setprio(1);                                                   \
    _Pragma("unroll") for (int mf = 0; mf < 4; ++mf)                                 \
      _Pragma("unroll") for (int nf = 0; nf < 2; ++nf) {                             \
        accG[mf + 4][nf] = MFMA_BF16(fWg[nf], fA[mf], accG[mf + 4][nf], 0, 0, 0);    \
        accU[mf + 4][nf] = MFMA_BF16(fWu[nf], fA[mf], accU[mf + 4][nf], 0, 0, 0);    \
      }                                                                              \
    __builtin_amdgcn_s_setprio(0);                                                   \
    if ((VM) >= 0) {                                                                 \
      asm volatile("s_waitcnt vmcnt(%0)" :: "i"((VM) < 0 ? 0 : (VM)) : "memory");    \
      __builtin_amdgcn_s_barrier();                                                  \
    }                                                                                \
  }

  // prologue: slices 0,1,2 in flight; wait slice 0
  GU_STG_A(0); GU_STG_W(0);
  GU_STG_A(1); GU_STG_W(1);
  GU_STG_A(2); GU_STG_W(2);
  asm volatile("s_waitcnt vmcnt(8)" ::: "memory");
  __builtin_amdgcn_s_barrier();

  for (int s = 0; s < S - 3; ++s) GU_SLICE(s, true, 8);
  GU_SLICE(S - 3, false, 4);
  GU_SLICE(S - 2, false, 0);
  GU_SLICE(S - 1, false, -1);
#undef GU_SLICE
#undef GU_STG_A
#undef GU_STG_W

  // epilogue: h = silu(g)*u*wrow -> bf16 hbuf
  const int lr4 = (lane >> 4) * 4;
#pragma unroll
  for (int mf = 0; mf < 8; ++mf) {
    const int grow = baseRow + wm * 128 + mf * 16 + ar;
    const float wf = wrow[grow];
#pragma unroll
    for (int nf = 0; nf < 2; ++nf) {
      const int n = n0 + wn * 32 + nf * 16 + lr4;
      f32x4 g = accG[mf][nf], u = accU[mf][nf];
      float h0 = silu_f(g[0]) * u[0] * wf;
      float h1 = silu_f(g[1]) * u[1] * wf;
      float h2 = silu_f(g[2]) * u[2] * wf;
      float h3 = silu_f(g[3]) * u[3] * wf;
      uint2 v;
      v.x = pk2(h0, h1);
      v.y = pk2(h2, h3);
      *(uint2*)(hbuf + ((size_t)grow * kI + n)) = v;
    }
  }
}

// ---------------- kernel 4: down GEMM, ring-4 slice pipeline ----------------
// BM=256, BN=256, slice=32K. 8 waves (2m x 4n), per-wave 128m x 64n.
// LDS slot (32 KiB): A [256][32] @0, W [256][32] @16384B.
// grid (kH/256, kCap/256, E), 512 threads.
__global__ __launch_bounds__(512, 2)
void gemm_dn_kernel(const unsigned short* __restrict__ hbuf,
                    const unsigned short* __restrict__ wdT,   // (E, H, I) bf16
                    const int* __restrict__ counts, const int* __restrict__ offs,
                    float* __restrict__ obuf) {
  constexpr int S = kI / 32;   // 128 slices
  __shared__ __attribute__((aligned(16))) unsigned short lds[4 * 16384];

  const int e   = blockIdx.z;
  const int cnt = counts[e];
  const int m0  = blockIdx.y * 256;
  if (m0 >= cnt) return;
  const int n0   = blockIdx.x * 256;
  const int tid  = threadIdx.x;
  const int lane = tid & 63;
  const int wv   = tid >> 6;
  const int wm   = wv >> 2;
  const int wn   = wv & 3;
  const int baseRow = offs[e] + m0;

  const int skof = ((tid & 3) ^ ((tid >> 3) & 3)) * 8;   // pre-swizzled source k
  const unsigned short* aP0 = hbuf + (size_t)(baseRow + (tid >> 2)) * kI + skof;
  const unsigned short* aP1 = hbuf + (size_t)(baseRow + 128 + (tid >> 2)) * kI + skof;
  const unsigned short* wP0 = wdT + (size_t)e * kH * kI
                                  + (size_t)(n0 + (tid >> 2)) * kI + skof;
  const unsigned short* wP1 = wdT + (size_t)e * kH * kI
                                  + (size_t)(n0 + 128 + (tid >> 2)) * kI + skof;
  char* ldsb = (char*)lds;
  const int cO0 = tid * 16;
  const int cO1 = cO0 + 8192;

#define DN_STG_A(s) { const int sb_ = ((s) & 3) * 32768; const int ko_ = (s) * 32;  \
    async_copy16(ldsb + sb_ + cO0, aP0 + ko_);                                      \
    async_copy16(ldsb + sb_ + cO1, aP1 + ko_); }
#define DN_STG_W(s) { const int sb_ = ((s) & 3) * 32768; const int ko_ = (s) * 32;  \
    async_copy16(ldsb + sb_ + 16384 + cO0, wP0 + ko_);                              \
    async_copy16(ldsb + sb_ + 16384 + cO1, wP1 + ko_); }

  f32x4 acc[8][4] = {};
  const int ar = lane & 15;
  const int fo = (((lane >> 4) ^ ((lane >> 1) & 3)) << 4);

#define DN_SLICE(s, STG, VM)                                                         \
  {                                                                                  \
    const char* sb = ldsb + ((s) & 3) * 32768;                                       \
    bf16x8 fA[4], fW[4];                                                             \
    _Pragma("unroll") for (int mf = 0; mf < 4; ++mf)                                 \
      fA[mf] = *(const bf16x8*)(sb + (wm * 128 + mf * 16 + ar) * 64 + fo);           \
    _Pragma("unroll") for (int nf = 0; nf < 4; ++nf)                                 \
      fW[nf] = *(const bf16x8*)(sb + 16384 + (wn * 64 + nf * 16 + ar) * 64 + fo);    \
    if (STG) DN_STG_A((s) + 3);                                                      \
    __builtin_amdgcn_s_barrier();                                                    \
    __builtin_amdgcn_s_setprio(1);                                                   \
    _Pragma("unroll") for (int mf = 0; mf < 4; ++mf)                                 \
      _Pragma("unroll") for (int nf = 0; nf < 4; ++nf)                               \
        acc[mf][nf] = MFMA_BF16(fW[nf], fA[mf], acc[mf][nf], 0, 0, 0);               \
    __builtin_amdgcn_s_setprio(0);                                                   \
    _Pragma("unroll") for (int mf = 0; mf < 4; ++mf)                                 \
      fA[mf] = *(const bf16x8*)(sb + (wm * 128 + (mf + 4) * 16 + ar) * 64 + fo);     \
    if (STG) DN_STG_W((s) + 3);                                                      \
    __builtin_amdgcn_s_barrier();                                                    \
    __builtin_amdgcn_s_setprio(1);                                                   \
    _Pragma("unroll") for (int mf = 0; mf < 4; ++mf)                                 \
      _Pragma("unroll") for (int nf = 0; nf < 4; ++nf)                               \
        acc[mf + 4][nf] = MFMA_BF16(fW[nf], fA[mf], acc[mf + 4][nf], 0, 0, 0);       \
    __builtin_amdgcn_s_setprio(0);                                                   \
    if ((VM) >= 0) {                                                                 \
      asm volatile("s_waitcnt vmcnt(%0)" :: "i"((VM) < 0 ? 0 : (VM)) : "memory");    \
      __builtin_amdgcn_s_barrier();                                                  \
    }                                                                                \
  }

  DN_STG_A(0); DN_STG_W(0);
  DN_STG_A(1); DN_STG_W(1);
  DN_STG_A(2); DN_STG_W(2);
  asm volatile("s_waitcnt vmcnt(8)" ::: "memory");
  __builtin_amdgcn_s_barrier();

  for (int s = 0; s < S - 3; ++s) DN_SLICE(s, true, 8);
  DN_SLICE(S - 3, false, 4);
  DN_SLICE(S - 2, false, 0);
  DN_SLICE(S - 1, false, -1);
#undef DN_SLICE
#undef DN_STG_A
#undef DN_STG_W

  const int lr4 = (lane >> 4) * 4;
#pragma unroll
  for (int mf = 0; mf < 8; ++mf) {
    const int grow = baseRow + wm * 128 + mf * 16 + ar;
#pragma unroll
    for (int nf = 0; nf < 4; ++nf) {
      const int n = n0 + wn * 64 + nf * 16 + lr4;
      *(f32x4*)(obuf + (size_t)grow * kH + n) = acc[mf][nf];
    }
  }
}

// ---------------- kernel 5: combine obuf slots -> out ----------------
__global__ void combine_kernel(const float* __restrict__ obuf,
                               const int* __restrict__ pos,
                               const int* __restrict__ offs,
                               float* __restrict__ out) {
  const int t   = blockIdx.y;
  const int col = blockIdx.x * 1024 + threadIdx.x * 4;
  const int c0  = pos[t * 2 + 0];
  const int c1  = pos[t * 2 + 1];
  const int row0 = offs[c0 >> 12] + (c0 & 4095);
  float4 v = *(const float4*)(obuf + (size_t)row0 * kH + col);
  if (c1 >= 0) {
    const int row1 = offs[c1 >> 12] + (c1 & 4095);
    float4 w = *(const float4*)(obuf + (size_t)row1 * kH + col);
    v.x += w.x; v.y += w.y; v.z += w.z; v.w += w.w;
  }
  *(float4*)(out + (size_t)t * kH + col) = v;
}

// ---------------- launcher ----------------
extern "C" void kernel_launch(void* const* d_in, const int* in_sizes, int n_in,
                              void* d_out, int out_size, void* d_ws, size_t ws_size,
                              hipStream_t stream) {
  const float* hs   = (const float*)d_in[0];
  const float* aff  = (const float*)d_in[1];
  const int*   eidx = (const int*)d_in[2];
  const float* wg   = (const float*)d_in[3];
  const float* wu   = (const float*)d_in[4];
  const float* wd   = (const float*)d_in[5];
  float* out = (float*)d_out;

  char* ws = (char*)d_ws;
  unsigned short* hsb  = (unsigned short*)(ws + HSB_OFF);
  unsigned short* hbuf = (unsigned short*)(ws + HBUF_OFF);
  unsigned short* wgT  = (unsigned short*)(ws + RA_OFF);   // later: wdT
  unsigned short* wdT  = (unsigned short*)(ws + RA_OFF);
  unsigned short* wuT  = (unsigned short*)(ws + RB_OFF);   // later: obuf
  float*          obuf = (float*)(ws + RB_OFF);
  int*            cnts = (int*)(ws + CNT_OFF);
  int*            offs = (int*)(ws + OFF_OFF);
  int*            ltok = (int*)(ws + LTOK_OFF);
  float*          lwgt = (float*)(ws + LW_OFF);
  int*            pos  = (int*)(ws + POS_OFF);
  float*          wrow = (float*)(ws + WROW_OFF);

  hipMemsetAsync(cnts, 0, kE * sizeof(int), stream);

  cvt_hs_kernel<<<(kT * kH) / (256 * 8), 256, 0, stream>>>(hs, hsb);
  route_kernel<<<kT / 256, 256, 0, stream>>>(aff, eidx, cnts, ltok, lwgt, pos);
  prefix_kernel<<<1, 64, 0, stream>>>(cnts, offs);
  wrow_kernel<<<(kE * kCap) / 256, 256, 0, stream>>>(cnts, offs, lwgt, wrow);

  tcvt_kernel<<<dim3(kI / 64, kH / 64, kE), 256, 0, stream>>>(wg, wgT, kH, kI);
  tcvt_kernel<<<dim3(kI / 64, kH / 64, kE), 256, 0, stream>>>(wu, wuT, kH, kI);

  gemm_gu_kernel<<<dim3(kI / 128, kCap / 256, kE), 512, 0, stream>>>(
      hsb, wgT, wuT, cnts, offs, ltok, wrow, hbuf);

  tcvt_kernel<<<dim3(kH / 64, kI / 64, kE), 256, 0, stream>>>(wd, wdT, kI, kH);

  gemm_dn_kernel<<<dim3(kH / 256, kCap / 256, kE), 512, 0, stream>>>(
      hbuf, wdT, cnts, offs, obuf);

  combine_kernel<<<dim3(kH / 1024, kT), 256, 0, stream>>>(obuf, pos, offs, out);
}